// Round 1
// baseline (298.493 us; speedup 1.0000x reference)
//
#include <hip/hip_runtime.h>

#define HH 384
#define HWPX (HH*HH)

// ---------------- xg = per-batch max(x) ----------------
__global__ void xg_init(float* ws) {
    if (threadIdx.x < 2) ws[threadIdx.x] = 0.f;
}

__global__ void xg_reduce(const float* __restrict__ x, float* ws) {
    const int per = 3 * HWPX;            // 442368
    int b = blockIdx.y;
    int chunk = blockIdx.x;
    int chunk_sz = per / gridDim.x;      // 2048 with 216 chunks
    int start = chunk * chunk_sz;
    float m = 0.f;
    for (int i = start + threadIdx.x; i < start + chunk_sz; i += blockDim.x)
        m = fmaxf(m, x[b * per + i]);
    for (int off = 32; off; off >>= 1)
        m = fmaxf(m, __shfl_down(m, off));
    __shared__ float sm[4];
    if ((threadIdx.x & 63) == 0) sm[threadIdx.x >> 6] = m;
    __syncthreads();
    if (threadIdx.x == 0) {
        int nw = blockDim.x >> 6;
        float mm = sm[0];
        for (int w = 1; w < nw; ++w) mm = fmaxf(mm, sm[w]);
        atomicMax((int*)&ws[b], __float_as_int(mm));   // x >= 0 so int-compare works
    }
}

// ---------------- attention-conv stage ----------------
// One thread per window. Input tile (reflect-padded) + all weights staged in LDS.
// d = c*P*P + r*P + s ; patch p = di*3+dj ; T(p,d) = tile[c][wy*P+di*P+r][wx*P+dj*P+s]
template <int P, int HEADS, int TW, int TH>
__global__ __launch_bounds__(TW * TH) void attn_kernel(
    const float* __restrict__ in, int in_bstride,
    float* __restrict__ out, int out_bstride,
    const float* __restrict__ Wq, const float* __restrict__ Bq,
    const float* __restrict__ Wk, const float* __restrict__ Bk,
    const float* __restrict__ Wv, const float* __restrict__ Bv,
    const float* __restrict__ HWt)
{
    constexpr int C = 3;
    constexpr int D = C * P * P;
    constexpr int TILE_H = (TH + 2) * P;
    constexpr int TILE_W = (TW + 2) * P;
    constexpr int NT = TW * TH;

    __shared__ float sW[3 * HEADS * D * D];
    __shared__ float sB[3 * HEADS * D];
    __shared__ float sHW[HEADS];
    __shared__ float tile[C][TILE_H][TILE_W];

    const int tid = threadIdx.x;
    for (int i = tid; i < HEADS * D * D; i += NT) {
        sW[i]                   = Wq[i];
        sW[HEADS * D * D + i]   = Wk[i];
        sW[2 * HEADS * D * D + i] = Wv[i];
    }
    for (int i = tid; i < HEADS * D; i += NT) {
        sB[i]                 = Bq[i];
        sB[HEADS * D + i]     = Bk[i];
        sB[2 * HEADS * D + i] = Bv[i];
    }
    if (tid < HEADS) sHW[tid] = HWt[tid];

    const int b = blockIdx.z;
    const int by = blockIdx.y * TH;
    const int bx = blockIdx.x * TW;
    const int base_y = by * P - P;
    const int base_x = bx * P - P;
    const float* inb = in + b * in_bstride;

    for (int i = tid; i < C * TILE_H * TILE_W; i += NT) {
        int c = i / (TILE_H * TILE_W);
        int rem = i % (TILE_H * TILE_W);
        int ty = rem / TILE_W, tx = rem % TILE_W;
        int y = base_y + ty; if (y < 0) y = -y; if (y >= HH) y = 2 * HH - 2 - y;
        int x = base_x + tx; if (x < 0) x = -x; if (x >= HH) x = 2 * HH - 2 - x;
        (&tile[0][0][0])[i] = inb[c * HWPX + y * HH + x];
    }
    __syncthreads();

    const int wx = tid % TW;
    const int wy = tid / TW;

    // center token
    float t4[D];
#pragma unroll
    for (int d = 0; d < D; ++d) {
        const int c = d / (P * P), r = (d / P) % P, s = d % P;
        t4[d] = tile[c][wy * P + P + r][wx * P + P + s];
    }

    float mixed[D];
#pragma unroll
    for (int e = 0; e < D; ++e) mixed[e] = 0.f;

    const float scale = rsqrtf((float)D);

    for (int h = 0; h < HEADS; ++h) {
        const float* wq = sW + h * D * D;
        const float* wk = sW + (HEADS + h) * D * D;
        const float* wv = sW + (2 * HEADS + h) * D * D;
        const float* bq = sB + h * D;
        const float* bk = sB + HEADS * D + h * D;
        const float* bv = sB + 2 * HEADS * D + h * D;

        float q[D];
#pragma unroll
        for (int e = 0; e < D; ++e) q[e] = bq[e];
#pragma unroll
        for (int d = 0; d < D; ++d) {
            float t = t4[d];
#pragma unroll
            for (int e = 0; e < D; ++e) q[e] += wq[e * D + d] * t;
        }

        float qk[D];
        float qb = 0.f;
#pragma unroll
        for (int d = 0; d < D; ++d) qk[d] = 0.f;
#pragma unroll
        for (int e = 0; e < D; ++e) {
            float qe = q[e];
            qb += qe * bk[e];
#pragma unroll
            for (int d = 0; d < D; ++d) qk[d] += qe * wk[e * D + d];
        }

        float score[9];
#pragma unroll
        for (int p = 0; p < 9; ++p) {
            const int di = p / 3, dj = p % 3;
            float s = qb;
#pragma unroll
            for (int d = 0; d < D; ++d) {
                const int c = d / (P * P), r = (d / P) % P, ss = d % P;
                s += qk[d] * tile[c][wy * P + di * P + r][wx * P + dj * P + ss];
            }
            score[p] = s * scale;
        }

        float m = score[0];
#pragma unroll
        for (int p = 1; p < 9; ++p) m = fmaxf(m, score[p]);
        float sum = 0.f;
#pragma unroll
        for (int p = 0; p < 9; ++p) { score[p] = __expf(score[p] - m); sum += score[p]; }
        float inv = 1.f / sum;

        float wt[D];
#pragma unroll
        for (int d = 0; d < D; ++d) wt[d] = 0.f;
#pragma unroll
        for (int p = 0; p < 9; ++p) {
            const int di = p / 3, dj = p % 3;
            float a = score[p] * inv;
#pragma unroll
            for (int d = 0; d < D; ++d) {
                const int c = d / (P * P), r = (d / P) % P, ss = d % P;
                wt[d] += a * tile[c][wy * P + di * P + r][wx * P + dj * P + ss];
            }
        }

        const float hwv = sHW[h];
#pragma unroll
        for (int e = 0; e < D; ++e) {
            float o = bv[e];
#pragma unroll
            for (int d = 0; d < D; ++d) o += wv[e * D + d] * wt[d];
            mixed[e] += hwv * o;
        }
    }

    float* outb = out + b * out_bstride;
#pragma unroll
    for (int d = 0; d < D; ++d) {
        const int c = d / (P * P), r = (d / P) % P, s = d % P;
        const int y = (by + wy) * P + r;
        const int x = (bx + wx) * P + s;
        outb[c * HWPX + y * HH + x] = mixed[d];
    }
}

// ---------------- conv0 (5x5, pad 2) + final elementwise ----------------
__global__ void conv_final_kernel(const float* __restrict__ cat,
                                  const float* __restrict__ w,
                                  const float* __restrict__ bias,
                                  const float* __restrict__ x,
                                  const float* __restrict__ xg,
                                  float* __restrict__ out)
{
    int idx = blockIdx.x * blockDim.x + threadIdx.x;
    const int total = 2 * 3 * HWPX;
    if (idx >= total) return;
    int b = idx / (3 * HWPX);
    int rem = idx % (3 * HWPX);
    int co = rem / HWPX;
    int pix = rem % HWPX;
    int y = pix / HH, xx = pix % HH;

    float acc = bias[co];
    const float* catb = cat + b * 9 * HWPX;
#pragma unroll
    for (int ky = 0; ky < 5; ++ky) {
        int yy = y + ky - 2;
        if (yy < 0 || yy >= HH) continue;
#pragma unroll
        for (int kx = 0; kx < 5; ++kx) {
            int xx2 = xx + kx - 2;
            if (xx2 < 0 || xx2 >= HH) continue;
            for (int ci = 0; ci < 9; ++ci)
                acc += catb[ci * HWPX + yy * HH + xx2] * w[(co * 9 + ci) * 25 + ky * 5 + kx];
        }
    }
    float x0 = fmaxf(acc, 0.f);
    float xv = x[idx];
    out[idx] = fmaxf(xv * x0 + xg[b] - x0, 0.f);
}

// ---------------- launch ----------------
extern "C" void kernel_launch(void* const* d_in, const int* in_sizes, int n_in,
                              void* d_out, int out_size, void* d_ws, size_t ws_size,
                              hipStream_t stream) {
    const float* x   = (const float*)d_in[0];
    const float* w3q = (const float*)d_in[1];
    const float* b3q = (const float*)d_in[2];
    const float* w3k = (const float*)d_in[3];
    const float* b3k = (const float*)d_in[4];
    const float* w3v = (const float*)d_in[5];
    const float* b3v = (const float*)d_in[6];
    const float* hw3 = (const float*)d_in[7];
    const float* w6q = (const float*)d_in[8];
    const float* b6q = (const float*)d_in[9];
    const float* w6k = (const float*)d_in[10];
    const float* b6k = (const float*)d_in[11];
    const float* w6v = (const float*)d_in[12];
    const float* b6v = (const float*)d_in[13];
    const float* hw6 = (const float*)d_in[14];
    const float* w9q = (const float*)d_in[15];
    const float* b9q = (const float*)d_in[16];
    const float* w9k = (const float*)d_in[17];
    const float* b9k = (const float*)d_in[18];
    const float* w9v = (const float*)d_in[19];
    const float* b9v = (const float*)d_in[20];
    const float* hw9 = (const float*)d_in[21];
    const float* c0w = (const float*)d_in[22];
    const float* c0b = (const float*)d_in[23];

    float* out = (float*)d_out;
    float* ws  = (float*)d_ws;
    float* xg  = ws;            // 2 floats
    float* cat = ws + 16;       // [2][9][384][384] floats = 10.6 MB

    xg_init<<<1, 64, 0, stream>>>(xg);
    xg_reduce<<<dim3(216, 2), 256, 0, stream>>>(x, xg);

    // stage3: p=1, 6 heads; in = x [B,3,H,W]; out -> cat channels 6..8
    attn_kernel<1, 6, 16, 16><<<dim3(384 / 16, 384 / 16, 2), 256, 0, stream>>>(
        x, 3 * HWPX, cat + 6 * HWPX, 9 * HWPX, w3q, b3q, w3k, b3k, w3v, b3v, hw3);
    // stage6: p=2, 4 heads; in = cat ch 6..8; out -> cat channels 3..5
    attn_kernel<2, 4, 16, 16><<<dim3(192 / 16, 192 / 16, 2), 256, 0, stream>>>(
        cat + 6 * HWPX, 9 * HWPX, cat + 3 * HWPX, 9 * HWPX, w6q, b6q, w6k, b6k, w6v, b6v, hw6);
    // stage9: p=3, 2 heads; in = cat ch 3..5; out -> cat channels 0..2
    attn_kernel<3, 2, 16, 8><<<dim3(128 / 16, 128 / 8, 2), 128, 0, stream>>>(
        cat + 3 * HWPX, 9 * HWPX, cat, 9 * HWPX, w9q, b9q, w9k, b9k, w9v, b9v, hw9);

    conv_final_kernel<<<(2 * 3 * HWPX + 255) / 256, 256, 0, stream>>>(
        cat, c0w, c0b, x, xg, out);
}

// Round 2
// 244.790 us; speedup vs baseline: 1.2194x; 1.2194x over previous
//
#include <hip/hip_runtime.h>

#define HH 384
#define HWPX (HH*HH)

// ws float-offset layout
#define WOFF3 16
#define HS3   40      // D=3,  DP=4 : 2*3*4  + 3*4  + 4
#define WOFF6 256     // 16 + 6*40
#define HS6   328     // D=12, DP=12: 2*12*12+ 3*12 + 4
#define WOFF9 1568    // 256 + 4*328
#define HS9   1600    // D=27, DP=28: 2*27*28+ 3*28 + 4
#define CATOFF 8192   // cat buffer starts here (floats)

// ---------------- precompute: fold Wq/Wk -> M, fold scale & head-weights ----------------
// per head: [M D*DP][WV D*DP][c DP][u DP][bvh DP][s0 pad4]
// qk[d] = c[d] + sum_a M[a*DP+d]*t4[a];  score_p = s0 + u.t4 + qk.T_p  (scale folded)
// out_e = bvh[e] + sum_d WV[e*DP+d]*wt[d]   (hw folded)
__global__ __launch_bounds__(256) void precompute_kernel(
    const float* __restrict__ w3q, const float* __restrict__ b3q,
    const float* __restrict__ w3k, const float* __restrict__ b3k,
    const float* __restrict__ w3v, const float* __restrict__ b3v, const float* __restrict__ hw3,
    const float* __restrict__ w6q, const float* __restrict__ b6q,
    const float* __restrict__ w6k, const float* __restrict__ b6k,
    const float* __restrict__ w6v, const float* __restrict__ b6v, const float* __restrict__ hw6,
    const float* __restrict__ w9q, const float* __restrict__ b9q,
    const float* __restrict__ w9k, const float* __restrict__ b9k,
    const float* __restrict__ w9v, const float* __restrict__ b9v, const float* __restrict__ hw9,
    float* __restrict__ ws)
{
    const int blk = blockIdx.x;
    const int tid = threadIdx.x;
    if (blk == 0 && tid == 0) { ws[0] = 0.f; ws[1] = 0.f; }  // xg slots (stream-ordered before xg_reduce)

    int stage = blk < 6 ? 0 : (blk < 10 ? 1 : 2);
    int h = blk - (stage == 0 ? 0 : (stage == 1 ? 6 : 10));
    const float* WQ[3] = {w3q, w6q, w9q};
    const float* BQ[3] = {b3q, b6q, b9q};
    const float* WK[3] = {w3k, w6k, w9k};
    const float* BK[3] = {b3k, b6k, b9k};
    const float* WV_[3] = {w3v, w6v, w9v};
    const float* BV[3] = {b3v, b6v, b9v};
    const float* HWp[3] = {hw3, hw6, hw9};
    const int Ds[3] = {3, 12, 27};
    const int DPs[3] = {4, 12, 28};
    const int WOFFs[3] = {WOFF3, WOFF6, WOFF9};
    const int HSs[3] = {HS3, HS6, HS9};

    const int D = Ds[stage], DP = DPs[stage];
    const float* wq = WQ[stage] + h * D * D;
    const float* bq = BQ[stage] + h * D;
    const float* wk = WK[stage] + h * D * D;
    const float* bk = BK[stage] + h * D;
    const float* wv = WV_[stage] + h * D * D;
    const float* bv = BV[stage] + h * D;
    const float hwv = HWp[stage][h];
    float* base = ws + WOFFs[stage] + h * HSs[stage];
    const float scale = rsqrtf((float)D);

    for (int i = tid; i < D * DP; i += 256) {
        int a = i / DP, b = i % DP;     // M[a][b]: qk[b] += M*t4[a]
        float m = 0.f;
        if (b < D) for (int e = 0; e < D; ++e) m += wk[e * D + b] * wq[e * D + a];
        base[i] = scale * m;
        float wvv = 0.f;                // WV[e=a][d=b]
        if (b < D) wvv = hwv * wv[a * D + b];
        base[D * DP + i] = wvv;
    }
    for (int i = tid; i < DP; i += 256) {
        float cv = 0.f, uv = 0.f;
        if (i < D) for (int e = 0; e < D; ++e) {
            cv += bq[e] * wk[e * D + i];
            uv += wq[e * D + i] * bk[e];
        }
        base[2 * D * DP + i] = scale * cv;
        base[2 * D * DP + DP + i] = scale * uv;
        base[2 * D * DP + 2 * DP + i] = (i < D) ? hwv * bv[i] : 0.f;
    }
    if (tid == 0) {
        float s = 0.f;
        for (int e = 0; e < D; ++e) s += bq[e] * bk[e];
        base[2 * D * DP + 3 * DP] = scale * s;
    }
}

// ---------------- xg = per-batch max(x) ----------------
__global__ void xg_reduce(const float* __restrict__ x, float* ws) {
    const int per = 3 * HWPX;
    int b = blockIdx.y;
    int chunk_sz = per / gridDim.x;
    int start = blockIdx.x * chunk_sz;
    float m = 0.f;
    for (int i = start + threadIdx.x; i < start + chunk_sz; i += blockDim.x)
        m = fmaxf(m, x[b * per + i]);
    for (int off = 32; off; off >>= 1)
        m = fmaxf(m, __shfl_down(m, off));
    __shared__ float sm[4];
    if ((threadIdx.x & 63) == 0) sm[threadIdx.x >> 6] = m;
    __syncthreads();
    if (threadIdx.x == 0) {
        int nw = blockDim.x >> 6;
        float mm = sm[0];
        for (int w = 1; w < nw; ++w) mm = fmaxf(mm, sm[w]);
        atomicMax((int*)&ws[b], __float_as_int(mm));   // x >= 0, ws zeroed by precompute
    }
}

// ---------------- attention stage v2 ----------------
template <int P, int HEADS, int TW, int TH, int SPLIT>
__global__ __launch_bounds__(TW * TH * SPLIT) void attn2(
    const float* __restrict__ in, int in_bstride,
    float* __restrict__ out, int out_bstride,
    const float* __restrict__ wsw)
{
    constexpr int C = 3;
    constexpr int D = C * P * P;
    constexpr int DP = (D + 3) & ~3;
    constexpr int HS = 2 * D * DP + 3 * DP + 4;
    constexpr int NW = TW * TH;
    constexpr int NT = NW * SPLIT;
    constexpr int HPT = HEADS / SPLIT;
    constexpr int TILE_H = (TH + 2) * P;
    constexpr int TILE_W = (TW + 2) * P;

    __shared__ float sw[HEADS * HS];
    __shared__ float tile[C][TILE_H][TILE_W];
    __shared__ float comb[(SPLIT > 1) ? NW * D : 1];

    const int tid = threadIdx.x;
    for (int i = tid; i < HEADS * HS; i += NT) sw[i] = wsw[i];

    const int b = blockIdx.z;
    const int by = blockIdx.y * TH;
    const int bx = blockIdx.x * TW;
    const int base_y = by * P - P;
    const int base_x = bx * P - P;
    const float* inb = in + b * in_bstride;

    for (int i = tid; i < C * TILE_H * TILE_W; i += NT) {
        int c = i / (TILE_H * TILE_W);
        int rem = i % (TILE_H * TILE_W);
        int ty = rem / TILE_W, tx = rem % TILE_W;
        int y = base_y + ty; if (y < 0) y = -y; if (y >= HH) y = 2 * HH - 2 - y;
        int x = base_x + tx; if (x < 0) x = -x; if (x >= HH) x = 2 * HH - 2 - x;
        (&tile[0][0][0])[i] = inb[c * HWPX + y * HH + x];
    }
    __syncthreads();

    const int w = tid & (NW - 1);
    const int h0 = (tid / NW) * HPT;
    const int wx = w % TW;
    const int wy = w / TW;

    float t4[D];
#pragma unroll
    for (int c = 0; c < C; ++c)
#pragma unroll
        for (int r = 0; r < P; ++r)
#pragma unroll
            for (int s = 0; s < P; ++s)
                t4[(c * P + r) * P + s] = tile[c][(wy + 1) * P + r][(wx + 1) * P + s];

    float mixed[D];
#pragma unroll
    for (int e = 0; e < D; ++e) mixed[e] = 0.f;

#pragma unroll
    for (int hh = 0; hh < HPT; ++hh) {
        const int h = h0 + hh;
        const float* M  = sw + h * HS;
        const float* WV = M + D * DP;
        const float* cc = M + 2 * D * DP;
        const float* uu = cc + DP;
        const float* bvh = cc + 2 * DP;
        const float s0 = cc[3 * DP];

        // qk = c + M^T t4 ; su = s0 + u.t4
        float qk[D];
#pragma unroll
        for (int d = 0; d < D; ++d) qk[d] = cc[d];
        float su = s0;
#pragma unroll
        for (int a = 0; a < D; ++a) {
            float t = t4[a];
            su += uu[a] * t;
#pragma unroll
            for (int d = 0; d < D; ++d) qk[d] += M[a * DP + d] * t;
        }

        // scores over 9 patches
        float sc[9];
#pragma unroll
        for (int di = 0; di < 3; ++di)
#pragma unroll
            for (int dj = 0; dj < 3; ++dj) {
                float s = su;
#pragma unroll
                for (int c = 0; c < C; ++c)
#pragma unroll
                    for (int r = 0; r < P; ++r)
#pragma unroll
                        for (int ss = 0; ss < P; ++ss)
                            s += qk[(c * P + r) * P + ss] *
                                 tile[c][(wy + di) * P + r][(wx + dj) * P + ss];
                sc[di * 3 + dj] = s;
            }

        float m = sc[0];
#pragma unroll
        for (int p = 1; p < 9; ++p) m = fmaxf(m, sc[p]);
        float sum = 0.f;
#pragma unroll
        for (int p = 0; p < 9; ++p) { sc[p] = __expf(sc[p] - m); sum += sc[p]; }
        float inv = 1.f / sum;

        // wt = sum_p a_p T_p
        float wt[D];
#pragma unroll
        for (int d = 0; d < D; ++d) wt[d] = 0.f;
#pragma unroll
        for (int di = 0; di < 3; ++di)
#pragma unroll
            for (int dj = 0; dj < 3; ++dj) {
                float a = sc[di * 3 + dj] * inv;
#pragma unroll
                for (int c = 0; c < C; ++c)
#pragma unroll
                    for (int r = 0; r < P; ++r)
#pragma unroll
                        for (int ss = 0; ss < P; ++ss)
                            wt[(c * P + r) * P + ss] += a *
                                tile[c][(wy + di) * P + r][(wx + dj) * P + ss];
            }

        // out_e = bvh + WV wt ; accumulate (hw already folded)
#pragma unroll
        for (int e = 0; e < D; ++e) {
            float o = bvh[e];
#pragma unroll
            for (int d = 0; d < D; ++d) o += WV[e * DP + d] * wt[d];
            mixed[e] += o;
        }
    }

    if (SPLIT > 1) {
        if (h0 != 0) {
#pragma unroll
            for (int e = 0; e < D; ++e) comb[w * D + e] = mixed[e];
        }
        __syncthreads();
        if (h0 != 0) return;
#pragma unroll
        for (int e = 0; e < D; ++e) mixed[e] += comb[w * D + e];
    }

    float* outb = out + b * out_bstride;
#pragma unroll
    for (int c = 0; c < C; ++c)
#pragma unroll
        for (int r = 0; r < P; ++r)
#pragma unroll
            for (int s = 0; s < P; ++s) {
                const int y = (by + wy) * P + r;
                const int x = (bx + wx) * P + s;
                outb[c * HWPX + y * HH + x] = mixed[(c * P + r) * P + s];
            }
}

// ---------------- conv0 (5x5, pad 2) + final elementwise, LDS-tiled ----------------
// block: 64x16 output region, 256 threads, each thread 3co x 4x outputs
__global__ __launch_bounds__(256) void conv_final(
    const float* __restrict__ cat, const float* __restrict__ w,
    const float* __restrict__ bias, const float* __restrict__ x,
    const float* __restrict__ xg, float* __restrict__ out)
{
    __shared__ float sw[675];            // [3][9][5][5]
    __shared__ float tile[9][20][76];    // rows 16B-aligned (76*4=304)
    const int tid = threadIdx.x;
    for (int i = tid; i < 675; i += 256) sw[i] = w[i];

    const int b = blockIdx.z;
    const int bx = blockIdx.x * 64;
    const int by = blockIdx.y * 16;
    const float* catb = cat + b * 9 * HWPX;

    for (int i = tid; i < 9 * 20 * 72; i += 256) {
        int ci = i / (20 * 72);
        int rem = i % (20 * 72);
        int row = rem / 72, col = rem % 72;
        int y = by + row - 2, xx = bx + col - 4;
        float v = 0.f;
        if (y >= 0 && y < HH && xx >= 0 && xx < HH) v = catb[ci * HWPX + y * HH + xx];
        tile[ci][row][col] = v;
    }
    __syncthreads();

    const int tx = tid & 15, ty = tid >> 4;
    float acc0[4], acc1[4], acc2[4];
    const float b0 = bias[0], b1 = bias[1], b2 = bias[2];
#pragma unroll
    for (int j = 0; j < 4; ++j) { acc0[j] = b0; acc1[j] = b1; acc2[j] = b2; }

#pragma unroll
    for (int ky = 0; ky < 5; ++ky) {
#pragma unroll
        for (int ci = 0; ci < 9; ++ci) {
            const float4 ra = *(const float4*)&tile[ci][ty + ky][4 * tx];
            const float4 rb = *(const float4*)&tile[ci][ty + ky][4 * tx + 4];
            const float4 rc = *(const float4*)&tile[ci][ty + ky][4 * tx + 8];
            const float r[12] = {ra.x, ra.y, ra.z, ra.w, rb.x, rb.y, rb.z, rb.w,
                                 rc.x, rc.y, rc.z, rc.w};
            const float* w0 = &sw[(0 * 9 + ci) * 25 + ky * 5];
            const float* w1 = &sw[(1 * 9 + ci) * 25 + ky * 5];
            const float* w2 = &sw[(2 * 9 + ci) * 25 + ky * 5];
#pragma unroll
            for (int j = 0; j < 4; ++j)
#pragma unroll
                for (int kx = 0; kx < 5; ++kx) {
                    const float t = r[j + kx + 2];
                    acc0[j] += t * w0[kx];
                    acc1[j] += t * w1[kx];
                    acc2[j] += t * w2[kx];
                }
        }
    }

    const int yb = by + ty, xb = bx + 4 * tx;
    const float xgv = xg[b];
    float* accs[3] = {acc0, acc1, acc2};
#pragma unroll
    for (int co = 0; co < 3; ++co) {
        const float4 xv = *(const float4*)&x[((size_t)(b * 3 + co)) * HWPX + yb * HH + xb];
        float4 ov;
        const float* a = accs[co];
        float x0;
        x0 = fmaxf(a[0], 0.f); ov.x = fmaxf(xv.x * x0 + xgv - x0, 0.f);
        x0 = fmaxf(a[1], 0.f); ov.y = fmaxf(xv.y * x0 + xgv - x0, 0.f);
        x0 = fmaxf(a[2], 0.f); ov.z = fmaxf(xv.z * x0 + xgv - x0, 0.f);
        x0 = fmaxf(a[3], 0.f); ov.w = fmaxf(xv.w * x0 + xgv - x0, 0.f);
        *(float4*)&out[((size_t)(b * 3 + co)) * HWPX + yb * HH + xb] = ov;
    }
}

// ---------------- launch ----------------
extern "C" void kernel_launch(void* const* d_in, const int* in_sizes, int n_in,
                              void* d_out, int out_size, void* d_ws, size_t ws_size,
                              hipStream_t stream) {
    const float* x   = (const float*)d_in[0];
    const float* w3q = (const float*)d_in[1];
    const float* b3q = (const float*)d_in[2];
    const float* w3k = (const float*)d_in[3];
    const float* b3k = (const float*)d_in[4];
    const float* w3v = (const float*)d_in[5];
    const float* b3v = (const float*)d_in[6];
    const float* hw3 = (const float*)d_in[7];
    const float* w6q = (const float*)d_in[8];
    const float* b6q = (const float*)d_in[9];
    const float* w6k = (const float*)d_in[10];
    const float* b6k = (const float*)d_in[11];
    const float* w6v = (const float*)d_in[12];
    const float* b6v = (const float*)d_in[13];
    const float* hw6 = (const float*)d_in[14];
    const float* w9q = (const float*)d_in[15];
    const float* b9q = (const float*)d_in[16];
    const float* w9k = (const float*)d_in[17];
    const float* b9k = (const float*)d_in[18];
    const float* w9v = (const float*)d_in[19];
    const float* b9v = (const float*)d_in[20];
    const float* hw9 = (const float*)d_in[21];
    const float* c0w = (const float*)d_in[22];
    const float* c0b = (const float*)d_in[23];

    float* out = (float*)d_out;
    float* ws  = (float*)d_ws;
    float* cat = ws + CATOFF;   // [2][9][384][384]

    precompute_kernel<<<12, 256, 0, stream>>>(
        w3q, b3q, w3k, b3k, w3v, b3v, hw3,
        w6q, b6q, w6k, b6k, w6v, b6v, hw6,
        w9q, b9q, w9k, b9k, w9v, b9v, hw9, ws);

    xg_reduce<<<dim3(216, 2), 256, 0, stream>>>(x, ws);

    // stage3: p=1, 6 heads -> cat ch 6..8
    attn2<1, 6, 16, 16, 1><<<dim3(24, 24, 2), 256, 0, stream>>>(
        x, 3 * HWPX, cat + 6 * HWPX, 9 * HWPX, ws + WOFF3);
    // stage6: p=2, 4 heads, head-split -> cat ch 3..5
    attn2<2, 4, 16, 8, 2><<<dim3(12, 24, 2), 256, 0, stream>>>(
        cat + 6 * HWPX, 9 * HWPX, cat + 3 * HWPX, 9 * HWPX, ws + WOFF6);
    // stage9: p=3, 2 heads, head-split -> cat ch 0..2
    attn2<3, 2, 8, 8, 2><<<dim3(16, 16, 2), 128, 0, stream>>>(
        cat + 3 * HWPX, 9 * HWPX, cat, 9 * HWPX, ws + WOFF9);

    conv_final<<<dim3(6, 24, 2), 256, 0, stream>>>(cat, c0w, c0b, x, ws, out);
}